// Round 7
// baseline (751.114 us; speedup 1.0000x reference)
//
#include <hip/hip_runtime.h>
#include <hip/hip_bf16.h>
#include <stdint.h>

typedef _Float16 f16x8 __attribute__((ext_vector_type(8)));
typedef _Float16 f16x4 __attribute__((ext_vector_type(4)));
typedef float    f32x4 __attribute__((ext_vector_type(4)));

// async 16-B global->LDS DMA: per-lane global src, dest = wave-uniform base + lane*16
#define GLDS16(gptr, lptr) \
  __builtin_amdgcn_global_load_lds((const __attribute__((address_space(1))) void*)(gptr), \
                                   (__attribute__((address_space(3))) void*)(lptr), 16, 0, 0)

// counted vmcnt wait (literal immediate), full memory clobber (rule #18)
#define WAITV(N) asm volatile("s_waitcnt vmcnt(" #N ")" ::: "memory")

// ---- tiled ("DMA-image") activation layout ----
// element (row, col) at: ((rb*4 + c)*8 + sub)*512 + r*8 + j   (halves)
// rb=row>>6, r=row&63, c=col>>6, sub=(col>>3)&7, j=col&7.
__device__ __forceinline__ int tile_off(int rb, int c, int sub) {
    return ((rb * 4 + c) * 8 + sub) * 512;
}

// WP layout: [c(8)][d0b(4)][g(4)][sub(8)][nl(64)][j(8)] halves.
__global__ __launch_bounds__(256) void prepack_weights(
    const float* __restrict__ Wih, const float* __restrict__ Whh,
    const float* __restrict__ bih, const float* __restrict__ bhh,
    _Float16* __restrict__ WP, float* __restrict__ BC)
{
    if (blockIdx.x == 2048) {
        int i = threadIdx.x;
        BC[i]       = bih[i] + bhh[i];
        BC[256 + i] = bih[256 + i] + bhh[256 + i];
        BC[512 + i] = bih[512 + i];
        BC[768 + i] = bhh[512 + i];
        return;
    }
    int idx = blockIdx.x * 256 + threadIdx.x;   // 524288 total
    int j   = idx & 7;
    int nl  = (idx >> 3) & 63;
    int sub = (idx >> 9) & 7;
    int g   = (idx >> 12) & 3;
    int d0b = (idx >> 14) & 3;
    int c   = idx >> 16;
    int k = c * 64 + sub * 8 + j;
    int d = d0b * 64 + nl;
    float v = 0.f;
    if (g == 0)      v = (k < 256) ? Wih[d * 256 + k]         : Whh[d * 256 + (k - 256)];
    else if (g == 1) v = (k < 256) ? Wih[(256 + d) * 256 + k] : Whh[(256 + d) * 256 + (k - 256)];
    else if (g == 2) v = (k < 256) ? Wih[(512 + d) * 256 + k] : 0.f;
    else             v = (k >= 256) ? Whh[(512 + d) * 256 + (k - 256)] : 0.f;
    WP[idx] = (_Float16)v;
}

// fp32 leaf -> fp16, split even/odd rows into TILED XE / XO buffers.
__global__ __launch_bounds__(256) void convert_split(
    const float* __restrict__ leaf, _Float16* __restrict__ XE, _Float16* __restrict__ XO)
{
    int g = blockIdx.x * 256 + threadIdx.x;     // 131072 rows * 32 units
    int u = g & 31;
    int row = g >> 5;
    const float* src = leaf + (size_t)row * 256 + u * 8;
    float4 a = *(const float4*)src;
    float4 b = *(const float4*)(src + 4);
    f16x8 p;
    p[0] = (_Float16)a.x; p[1] = (_Float16)a.y; p[2] = (_Float16)a.z; p[3] = (_Float16)a.w;
    p[4] = (_Float16)b.x; p[5] = (_Float16)b.y; p[6] = (_Float16)b.z; p[7] = (_Float16)b.w;
    int ro = row >> 1;
    _Float16* dst = (row & 1) ? XO : XE;
    *(f16x8*)(dst + tile_off(ro >> 6, u >> 3, u & 7) + (ro & 63) * 8) = p;
}

// Big-level GRU cell (round-4 proven, unchanged). MT=8 only.
template<int MT, bool SWIZ>
__global__ __launch_bounds__(256, 2) void gru_cell(
    const _Float16* __restrict__ Xsrc,
    const _Float16* __restrict__ Hsrc,
    const _Float16* __restrict__ WP,
    const float* __restrict__ BC,
    _Float16* __restrict__ Hout,
    _Float16* __restrict__ Ee, _Float16* __restrict__ Eo, _Float16* __restrict__ HP,
    int M)
{
    (void)M;
    constexpr int AROW = MT * 16 * 8;
    constexpr int ASZ  = 8 * AROW;
    __shared__ __align__(16) _Float16 Alds[2 * ASZ];

    const int tid  = threadIdx.x;
    int bm, d0b;
    if (SWIZ) {
        int xcd = blockIdx.x & 7, slot = blockIdx.x >> 3;
        d0b = slot & 3;
        bm  = (slot >> 2) * 8 + xcd;
    } else {
        bm = blockIdx.x >> 2; d0b = blockIdx.x & 3;
    }
    const int wave = tid >> 6, lane = tid & 63;
    const int quad = lane >> 4, lo = lane & 15;

    const bool has_h = (Hsrc != nullptr);
    const int nch = has_h ? 8 : 4;

    f32x4 acc[MT][4];
#pragma unroll
    for (int a = 0; a < MT; ++a)
#pragma unroll
        for (int b = 0; b < 4; ++b) acc[a][b] = (f32x4){0.f, 0.f, 0.f, 0.f};
    f16x4 hinvh[MT];

    auto loadB = [&](int c, f16x8 (&bb)[2][3]) {
        const size_t cb = (size_t)(c * 4 + d0b) * 4;
        const int col = (wave * 16 + lo) * 8;
#pragma unroll
        for (int ks = 0; ks < 2; ++ks) {
            const int subb = ks * 4 + quad;
#pragma unroll
            for (int slot = 0; slot < 3; ++slot) {
                int g = (slot == 2) ? ((c < 4) ? 2 : 3) : slot;
                bb[ks][slot] = *(const f16x8*)(WP + ((cb + g) * 8 + subb) * 512 + col);
            }
        }
    };

    auto issueA = [&](int c, int buf) {
        const _Float16* base = (c < 4) ? Xsrc : Hsrc;
        const int cc = c & 3;
        _Float16* Ab = Alds + buf * ASZ;
        constexpr int ND = MT / 2;
#pragma unroll
        for (int i = 0; i < ND; ++i) {
            int ai = wave * ND + i;
            int sub = ai >> 1, mh = ai & 1;
            GLDS16(base + tile_off(bm * (MT / 4) + mh, cc, sub) + lane * 8,
                   Ab + sub * AROW + mh * 512);
        }
    };

    auto compute = [&](int c, int buf, f16x8 (&bb)[2][3]) {
        const _Float16* Ab = Alds + buf * ASZ;
#pragma unroll
        for (int ks = 0; ks < 2; ++ks) {
            const int subb = ks * 4 + quad;
#pragma unroll
            for (int mt = 0; mt < MT; ++mt) {
                f16x8 a = *(const f16x8*)(Ab + subb * AROW + (mt * 16 + lo) * 8);
                acc[mt][0] = __builtin_amdgcn_mfma_f32_16x16x32_f16(a, bb[ks][0], acc[mt][0], 0, 0, 0);
                acc[mt][1] = __builtin_amdgcn_mfma_f32_16x16x32_f16(a, bb[ks][1], acc[mt][1], 0, 0, 0);
                if (c < 4)
                    acc[mt][2] = __builtin_amdgcn_mfma_f32_16x16x32_f16(a, bb[ks][2], acc[mt][2], 0, 0, 0);
                else
                    acc[mt][3] = __builtin_amdgcn_mfma_f32_16x16x32_f16(a, bb[ks][2], acc[mt][3], 0, 0, 0);
            }
        }
        if (has_h && c == 4 + d0b) {
            const int colw = wave * 16 + lo;
            const int sub = colw >> 3, j = colw & 7;
#pragma unroll
            for (int mt = 0; mt < MT; ++mt)
#pragma unroll
                for (int r = 0; r < 4; ++r)
                    hinvh[mt][r] = Ab[sub * AROW + (mt * 16 + quad * 4 + r) * 8 + j];
        }
    };

    issueA(0, 0);
    for (int c = 0; c < nch; ++c) {
        __syncthreads();
        f16x8 bb[2][3];
        loadB(c, bb);
        __builtin_amdgcn_sched_barrier(0);
        if (c + 1 < nch) issueA(c + 1, (c + 1) & 1);
        compute(c, c & 1, bb);
    }

    const int ld = wave * 16 + lo;
    const int d  = d0b * 64 + ld;
    const float brz0 = BC[d];
    const float brz1 = BC[256 + d];
    const float bni  = BC[512 + d];
    const float bnh  = BC[768 + d];
    constexpr int SROW = 72;
    constexpr int PR   = MT * 8;
    __syncthreads();
#pragma unroll
    for (int mt = 0; mt < MT; ++mt) {
        const int lr0 = mt * 16 + quad * 4;
        float hq[4];
#pragma unroll
        for (int r = 0; r < 4; ++r) {
            float hin = has_h ? (float)hinvh[mt][r] : 0.f;
            float rg = 1.f / (1.f + __expf(-(acc[mt][0][r] + brz0)));
            float zg = 1.f / (1.f + __expf(-(acc[mt][1][r] + brz1)));
            float ex = __expf(2.f * (acc[mt][2][r] + bni + rg * (acc[mt][3][r] + bnh)));
            float nv = 1.f - 2.f / (ex + 1.f);
            hq[r] = (1.f - zg) * nv + zg * hin;
            int lr = lr0 + r;
            if (Hout) {
                Alds[lr * SROW + ld] = (_Float16)hq[r];
            } else {
                Alds[(((lr & 1) * PR) + (lr >> 1)) * SROW + ld] =
                    (_Float16)(0.5f * (hin + hq[r]));
            }
        }
        if (!Hout) {
            Alds[(2 * PR + (lr0 >> 1)) * SROW + ld]     = (_Float16)(0.5f * (hq[0] + hq[1]));
            Alds[(2 * PR + (lr0 >> 1) + 1) * SROW + ld] = (_Float16)(0.5f * (hq[2] + hq[3]));
        }
    }
    __syncthreads();

    if (Hout) {
        constexpr int NU = MT * 128;
#pragma unroll
        for (int i = 0; i < NU / 256; ++i) {
            int uid = i * 256 + tid;
            int r = uid & 63, sub = (uid >> 6) & 7, mh = uid >> 9;
            f16x8 v = *(const f16x8*)&Alds[(mh * 64 + r) * SROW + sub * 8];
            *(f16x8*)(Hout + tile_off(bm * (MT / 4) + mh, d0b, sub) + r * 8) = v;
        }
    } else {
        constexpr int NU = 3 * PR * 8;
#pragma unroll
        for (int i = 0; i < NU / 256; ++i) {
            int uid = i * 256 + tid;
            int pr   = uid & (PR - 1);
            int rest = uid / PR;
            int sub = rest & 7, buf = rest >> 3;
            f16x8 v = *(const f16x8*)&Alds[(buf * PR + pr) * SROW + sub * 8];
            _Float16* dst = (buf == 0) ? Ee : (buf == 1) ? Eo : HP;
            *(f16x8*)(dst + tile_off(bm, d0b, sub) + pr * 8) = v;
        }
    }
}

// ---- fused tail level: cell1 + cell2 for 16 rows x ALL 256 dims per block ----
// Wave w owns dims w*64..w*64+63 (4 n-tiles of 16). h1 never leaves the block:
// computed in registers, staged in H1i (A-image layout), consumed as cell2's
// A-operand for chunks 4..7 (no DMA, no barriers there).
// B loaded to registers BEFORE the A-DMA issue (counted-vmcnt trick, round 4).
// For the last level (out != null) the E values ARE the final answer -> fp32 out.
__global__ __launch_bounds__(256, 1) void gru_tail16(
    const _Float16* __restrict__ Xe, const _Float16* __restrict__ Xo,
    const _Float16* __restrict__ HPs,
    const _Float16* __restrict__ WP, const float* __restrict__ BC,
    _Float16* __restrict__ Ee, _Float16* __restrict__ Eo,
    _Float16* __restrict__ HPd, float* __restrict__ out)
{
    __shared__ __align__(16) _Float16 A[3][1024];     // 3 bufs x (8 sub x 16 row x 8)
    __shared__ __align__(16) _Float16 H1i[4][1024];   // h1 A-image, 4 k-chunks

    const int tid  = threadIdx.x;
    const int wave = tid >> 6, lane = tid & 63;
    const int quad = lane >> 4, lo = lane & 15;
    const int bid  = blockIdx.x;
    const int m0 = bid * 16, rb = m0 >> 6, ro = m0 & 63;

    float brz0[4], brz1[4], bni[4], bnh[4];
#pragma unroll
    for (int nt = 0; nt < 4; ++nt) {
        int d = wave * 64 + nt * 16 + lo;
        brz0[nt] = BC[d];       brz1[nt] = BC[256 + d];
        bni[nt]  = BC[512 + d]; bnh[nt]  = BC[768 + d];
    }

    f32x4 acc[4][4];
    auto zacc = [&] {
#pragma unroll
        for (int nt = 0; nt < 4; ++nt)
#pragma unroll
            for (int g = 0; g < 4; ++g) acc[nt][g] = (f32x4){0.f, 0.f, 0.f, 0.f};
    };

    // one DMA per wave per chunk (waves 0,1 -> sub-half 0; waves 2,3 -> half 1;
    // 2x duplication, identical data -> benign). src: 16-row slice of 4 units.
    auto issueA = [&](const _Float16* base, int cc, int buf) {
        const int i = wave >> 1;
        GLDS16(base + tile_off(rb, cc, i * 4 + (lane >> 4)) + (ro + (lane & 15)) * 8,
               &A[buf][i * 512]);
    };

    auto loadB = [&](int c, f16x8 (&bb)[2][4][3]) {
#pragma unroll
        for (int ks = 0; ks < 2; ++ks) {
            const int subq = ks * 4 + quad;
            const _Float16* wb = WP + (size_t)((c * 4 + wave) * 4) * 4096 + subq * 512;
#pragma unroll
            for (int nt = 0; nt < 4; ++nt) {
                const int colb = (nt * 16 + lo) * 8;
                bb[ks][nt][0] = *(const f16x8*)(wb + colb);
                bb[ks][nt][1] = *(const f16x8*)(wb + 4096 + colb);
                bb[ks][nt][2] = *(const f16x8*)(wb + ((c < 4) ? 2 : 3) * 4096 + colb);
            }
        }
    };

    auto mfmaC = [&](int c, const _Float16* Ab, f16x8 (&bb)[2][4][3]) {
#pragma unroll
        for (int ks = 0; ks < 2; ++ks) {
            const int subq = ks * 4 + quad;
            f16x8 a = *(const f16x8*)(Ab + subq * 128 + lo * 8);
#pragma unroll
            for (int nt = 0; nt < 4; ++nt) {
                acc[nt][0] = __builtin_amdgcn_mfma_f32_16x16x32_f16(a, bb[ks][nt][0], acc[nt][0], 0, 0, 0);
                acc[nt][1] = __builtin_amdgcn_mfma_f32_16x16x32_f16(a, bb[ks][nt][1], acc[nt][1], 0, 0, 0);
                if (c < 4)
                    acc[nt][2] = __builtin_amdgcn_mfma_f32_16x16x32_f16(a, bb[ks][nt][2], acc[nt][2], 0, 0, 0);
                else
                    acc[nt][3] = __builtin_amdgcn_mfma_f32_16x16x32_f16(a, bb[ks][nt][2], acc[nt][3], 0, 0, 0);
            }
        }
    };

    // ---- cell 1: chunks 0..3 from Xe, 4..7 from HPs ----
    zacc();
    float hin[4][4];
    issueA(Xe, 0, 0);
    issueA(Xe, 1, 1);
    for (int c = 0; c < 8; ++c) {
        if (c < 7) WAITV(1); else WAITV(0);
        __builtin_amdgcn_s_barrier();
        __builtin_amdgcn_sched_barrier(0);
        f16x8 bb[2][4][3];
        loadB(c, bb);
        __builtin_amdgcn_sched_barrier(0);
        if (c + 2 < 8) {
            int cn = c + 2;
            issueA((cn < 4) ? Xe : HPs, cn & 3, cn % 3);
        }
        const _Float16* Ab = A[c % 3];
        mfmaC(c, Ab, bb);
        if (c == 4 + wave) {            // capture hin for this wave's dims
#pragma unroll
            for (int nt = 0; nt < 4; ++nt) {
                const int sb = nt * 2 + (lo >> 3), j = lo & 7;
#pragma unroll
                for (int r = 0; r < 4; ++r)
                    hin[nt][r] = (float)Ab[sb * 128 + (quad * 4 + r) * 8 + j];
            }
        }
    }

    __syncthreads();                    // all waves done with A bufs
    float h1v[4][4];
#pragma unroll
    for (int nt = 0; nt < 4; ++nt) {
        const int sb = nt * 2 + (lo >> 3), j = lo & 7;
#pragma unroll
        for (int r = 0; r < 4; ++r) {
            float rg = 1.f / (1.f + __expf(-(acc[nt][0][r] + brz0[nt])));
            float zg = 1.f / (1.f + __expf(-(acc[nt][1][r] + brz1[nt])));
            float ex = __expf(2.f * (acc[nt][2][r] + bni[nt] + rg * (acc[nt][3][r] + bnh[nt])));
            float nv = 1.f - 2.f / (ex + 1.f);
            float h  = (1.f - zg) * nv + zg * hin[nt][r];
            h1v[nt][r] = h;
            H1i[wave][sb * 128 + (quad * 4 + r) * 8 + j] = (_Float16)h;
        }
    }
    __syncthreads();                    // H1i visible to all waves

    // ---- cell 2: chunks 0..3 from Xo (DMA), 4..7 from H1i (LDS-direct) ----
    zacc();
    issueA(Xo, 0, 0);
    issueA(Xo, 1, 1);
    for (int c = 0; c < 4; ++c) {
        if (c < 3) WAITV(1); else WAITV(0);
        __builtin_amdgcn_s_barrier();
        __builtin_amdgcn_sched_barrier(0);
        f16x8 bb[2][4][3];
        loadB(c, bb);
        __builtin_amdgcn_sched_barrier(0);
        if (c + 2 < 4) issueA(Xo, c + 2, (c + 2) % 3);
        mfmaC(c, A[c % 3], bb);
    }
#pragma unroll
    for (int c = 4; c < 8; ++c) {
        f16x8 bb[2][4][3];
        loadB(c, bb);
        mfmaC(c, &H1i[c - 4][0], bb);
    }

    // ---- epilogue: h2, then E (or final out) + HP, direct from registers ----
#pragma unroll
    for (int nt = 0; nt < 4; ++nt) {
        const int sb = nt * 2 + (lo >> 3), j = lo & 7;
        float h2[4];
#pragma unroll
        for (int r = 0; r < 4; ++r) {
            float rg = 1.f / (1.f + __expf(-(acc[nt][0][r] + brz0[nt])));
            float zg = 1.f / (1.f + __expf(-(acc[nt][1][r] + brz1[nt])));
            float ex = __expf(2.f * (acc[nt][2][r] + bni[nt] + rg * (acc[nt][3][r] + bnh[nt])));
            float nv = 1.f - 2.f / (ex + 1.f);
            h2[r] = (1.f - zg) * nv + zg * h1v[nt][r];
        }
        if (out) {
#pragma unroll
            for (int r = 0; r < 4; ++r)
                out[(size_t)(m0 + quad * 4 + r) * 256 + wave * 64 + nt * 16 + lo] =
                    0.5f * (h1v[nt][r] + h2[r]);
        } else {
            const int rbE   = bid >> 3;
            const int rbase = (bid & 7) * 8 + quad * 2;
            const int toff  = tile_off(rbE, wave, sb);
#pragma unroll
            for (int r = 0; r < 4; ++r) {
                _Float16* dst = (r & 1) ? Eo : Ee;
                dst[toff + (rbase + (r >> 1)) * 8 + j] =
                    (_Float16)(0.5f * (h1v[nt][r] + h2[r]));
            }
            HPd[toff + rbase * 8 + j]       = (_Float16)(0.5f * (h2[0] + h2[1]));
            HPd[toff + (rbase + 1) * 8 + j] = (_Float16)(0.5f * (h2[2] + h2[3]));
        }
    }
}

extern "C" void kernel_launch(void* const* d_in, const int* in_sizes, int n_in,
                              void* d_out, int out_size, void* d_ws, size_t ws_size,
                              hipStream_t stream) {
    const float* leaf = (const float*)d_in[0];
    const float* Wih  = (const float*)d_in[1];
    const float* Whh  = (const float*)d_in[2];
    const float* bih  = (const float*)d_in[3];
    const float* bhh  = (const float*)d_in[4];

    char* ws = (char*)d_ws;
    _Float16* WPp = (_Float16*)ws;                         //  1 MB
    _Float16* XAe = (_Float16*)(ws + (1ull  << 20));       // 32 MB
    _Float16* XAo = (_Float16*)(ws + (33ull << 20));       // 32 MB
    _Float16* XBe = (_Float16*)(ws + (65ull << 20));       // 16 MB
    _Float16* XBo = (_Float16*)(ws + (81ull << 20));       // 16 MB
    _Float16* H1  = (_Float16*)(ws + (97ull << 20));       // 32 MB (big levels only)
    _Float16* HP2 = (_Float16*)(ws + (113ull << 20));      // tail HP ping (inside H1 span, time-disjoint)
    _Float16* HPb = (_Float16*)(ws + (129ull << 20));      // 16 MB
    float*    BCp = (float*)(ws + (145ull << 20));         //  4 KB

    prepack_weights<<<2049, 256, 0, stream>>>(Wih, Whh, bih, bhh, WPp, BCp);
    convert_split<<<16384, 256, 0, stream>>>(leaf, XAe, XAo);

    // big levels 0..3 (proven round-4 structure)
    _Float16 *XeC = XAe, *XoC = XAo, *XeN = XBe, *XoN = XBo;
    const _Float16* hp = nullptr;
    int M = 65536;
    for (int lev = 0; lev < 4; ++lev) {
        int grid = (M / 128) * 4;
        gru_cell<8, true><<<grid, 256, 0, stream>>>(XeC, hp, WPp, BCp,
                                                    H1, nullptr, nullptr, nullptr, M);
        gru_cell<8, true><<<grid, 256, 0, stream>>>(XoC, H1, WPp, BCp,
                                                    nullptr, XeN, XoN, HPb, M);
        hp = HPb;
        _Float16* t;
        t = XeC; XeC = XeN; XeN = t;
        t = XoC; XoC = XoN; XoN = t;
        M >>= 1;
    }
    // after 4 swaps: lev-3 output in XAe/XAo, HPb holds its pair-avg.

    // tail levels 4..11: one fused launch per level, no cross-block deps
    for (int lev = 4; lev <= 11; ++lev) {
        int nb = (65536 >> lev) / 16;              // 256,128,...,2
        _Float16* Xe = (lev & 1) ? XBe : XAe;
        _Float16* Xo = (lev & 1) ? XBo : XAo;
        _Float16* De = (lev & 1) ? XAe : XBe;
        _Float16* Do = (lev & 1) ? XAo : XBo;
        _Float16* HPsrc = (lev & 1) ? HP2 : HPb;
        _Float16* HPdst = (lev & 1) ? HPb : HP2;
        float* op = (lev == 11) ? (float*)d_out : nullptr;
        gru_tail16<<<nb, 256, 0, stream>>>(Xe, Xo, HPsrc, WPp, BCp,
                                           De, Do, HPdst, op);
    }
}